// Round 2
// baseline (4012.128 us; speedup 1.0000x reference)
//
#include <hip/hip_runtime.h>
#include <math.h>

#define BATCH 32768
#define NVARS 50
#define H1 1024
#define H2 1024
#define H3 256
#define NOUT 100
#define EPSBN 1e-5f

// A_control structural constants (f32-rounded exactly as numpy produces them)
#define TF   0.05f
#define AF   20.0f
#define JF   400.0f
#define VMAX 1.0f
#define AMAX 2.0f
#define JMAX 5.0f
#define PMAX 3.14159265358979323846f  // rounds to float32(pi)

// ---------------------------------------------------------------------------
// All scratch lives in device globals: no dependence on ws_size at all.
// ---------------------------------------------------------------------------
__device__ float g_z1[(size_t)BATCH * H1];   // 128 MiB: z1 / (z3, nno reuse)
__device__ float g_z2[(size_t)BATCH * H2];   // 128 MiB
__device__ float g_ps[32 * 1024];
__device__ float g_pq[32 * 1024];
__device__ float g_scale[3 * 1024];
__device__ float g_shift[3 * 1024];
__device__ float g_Mi[2500];

// ---------------------------------------------------------------------------
// Build M = Q_inv[0:50, 0:50] via f64 Gauss-Jordan with partial pivoting.
// Q = [[I + 2*(Pv^T Pv + Pa^T Pa + Pj^T Pj + Pp^T Pp), A_eq^T], [A_eq, 0]]
// (factor 2 because A_control stacks +block and -block).
// ---------------------------------------------------------------------------
__global__ void build_M(float* __restrict__ Mout)
{
    __shared__ double aug[52][104];
    __shared__ int piv;
    int tid = threadIdx.x;

    if (tid == 0) {
        for (int j = 0; j < 52; ++j)
            for (int k = 0; k < 104; ++k)
                aug[j][k] = (k == 52 + j) ? 1.0 : 0.0;

        double T = 0.05, a = 1.0 / T;
        float af = (float)a, jf = (float)(a / T), Tf = (float)T;

        // eye + vel (2*af^2... vel block is identity: 2*1)
        for (int j = 0; j < 50; ++j)
            aug[j][j] += 1.0 + 2.0;
        // acc stencil (-af, +af)
        {
            double c2[2] = { -(double)af, (double)af };
            for (int i = 0; i < 49; ++i)
                for (int dj = 0; dj < 2; ++dj)
                    for (int dk = 0; dk < 2; ++dk)
                        aug[i + dj][i + dk] += 2.0 * c2[dj] * c2[dk];
        }
        // jerk stencil (jf, -2jf, jf)
        {
            double c3[3] = { (double)jf, -2.0 * (double)jf, (double)jf };
            for (int i = 0; i < 48; ++i)
                for (int dj = 0; dj < 3; ++dj)
                    for (int dk = 0; dk < 3; ++dk)
                        aug[i + dj][i + dk] += 2.0 * c3[dj] * c3[dk];
        }
        // pos: (Pp^T Pp)[j][k] = T^2 * (50 - max(j,k))
        for (int j = 0; j < 50; ++j)
            for (int k = 0; k < 50; ++k)
                aug[j][k] += 2.0 * (double)Tf * (double)Tf * (double)(50 - (j > k ? j : k));
        // A_eq
        aug[50][0] = 1.0; aug[0][50] = 1.0;
        aug[51][49] = 1.0; aug[49][51] = 1.0;
    }
    __syncthreads();

    for (int c = 0; c < 52; ++c) {
        if (tid == 0) {
            int p = c; double best = fabs(aug[c][c]);
            for (int r = c + 1; r < 52; ++r) {
                double v = fabs(aug[r][c]);
                if (v > best) { best = v; p = r; }
            }
            piv = p;
        }
        __syncthreads();
        int p = piv;
        if (p != c) {
            for (int k = tid; k < 104; k += 64) {
                double t = aug[c][k]; aug[c][k] = aug[p][k]; aug[p][k] = t;
            }
        }
        __syncthreads();
        double pv = aug[c][c];
        __syncthreads();
        for (int k = tid; k < 104; k += 64) aug[c][k] /= pv;
        __syncthreads();
        if (tid < 52 && tid != c) {
            double f = aug[tid][c];
            for (int k = 0; k < 104; ++k) aug[tid][k] -= f * aug[c][k];
        }
        __syncthreads();
    }

    for (int idx = tid; idx < 2500; idx += 64) {
        int j = idx / 50, k = idx % 50;
        Mout[idx] = (float)aug[j][52 + k];
    }
}

// ---------------------------------------------------------------------------
// fp32 tiled GEMM: C[M,N] = act(A) @ W + bias.
// If BN_APPLY: act(a_col_k) = relu(a * scale[k] + shift[k])  (folded batchnorm)
// BM=BN=128, BK=16, 256 threads, 8x8 per thread.
// ---------------------------------------------------------------------------
template <int BN_APPLY>
__global__ __launch_bounds__(256)
void gemm_k(const float* __restrict__ A, const float* __restrict__ W,
            const float* __restrict__ bias,
            const float* __restrict__ scale, const float* __restrict__ shift,
            float* __restrict__ C, int M, int K, int N)
{
    const int BM = 128, BN = 128, BK = 16;
    __shared__ __attribute__((aligned(16))) float As[BK][BM + 4];
    __shared__ __attribute__((aligned(16))) float Ws[BK][BN];
    int tid = threadIdx.x;
    int tm = tid >> 4, tn = tid & 15;
    int row0 = blockIdx.x * BM, col0 = blockIdx.y * BN;

    float acc[8][8];
#pragma unroll
    for (int i = 0; i < 8; ++i)
#pragma unroll
        for (int j = 0; j < 8; ++j) acc[i][j] = 0.f;

    int alr = tid >> 4;   // 0..15 row slot
    int alk = tid & 15;   // 0..15 k slot
    int wlc = tid & 127;  // 0..127 col
    int wlk = tid >> 7;   // 0..1 k slot

    for (int k0 = 0; k0 < K; k0 += BK) {
#pragma unroll
        for (int i = 0; i < 8; ++i) {
            int r = row0 + alr + i * 16;
            int kk = k0 + alk;
            float v = 0.f;
            if (kk < K) {
                v = A[(size_t)r * K + kk];
                if (BN_APPLY) v = fmaxf(v * scale[kk] + shift[kk], 0.f);
            }
            As[alk][alr + i * 16] = v;
        }
#pragma unroll
        for (int i = 0; i < 8; ++i) {
            int kk = k0 + wlk + i * 2;
            int c = col0 + wlc;
            Ws[wlk + i * 2][wlc] = (kk < K && c < N) ? W[(size_t)kk * N + c] : 0.f;
        }
        __syncthreads();
#pragma unroll
        for (int kk = 0; kk < BK; ++kk) {
            float av[8], wv[8];
            float4 t;
            t = *(const float4*)&As[kk][tm * 8];     av[0]=t.x; av[1]=t.y; av[2]=t.z; av[3]=t.w;
            t = *(const float4*)&As[kk][tm * 8 + 4]; av[4]=t.x; av[5]=t.y; av[6]=t.z; av[7]=t.w;
            t = *(const float4*)&Ws[kk][tn * 8];     wv[0]=t.x; wv[1]=t.y; wv[2]=t.z; wv[3]=t.w;
            t = *(const float4*)&Ws[kk][tn * 8 + 4]; wv[4]=t.x; wv[5]=t.y; wv[6]=t.z; wv[7]=t.w;
#pragma unroll
            for (int i = 0; i < 8; ++i)
#pragma unroll
                for (int j = 0; j < 8; ++j) acc[i][j] += av[i] * wv[j];
        }
        __syncthreads();
    }
#pragma unroll
    for (int i = 0; i < 8; ++i) {
        int r = row0 + tm * 8 + i;
#pragma unroll
        for (int j = 0; j < 8; ++j) {
            int c = col0 + tn * 8 + j;
            if (c < N) C[(size_t)r * N + c] = acc[i][j] + bias[c];
        }
    }
}

// ---------------------------------------------------------------------------
// BatchNorm stats, two deterministic stages.
// ---------------------------------------------------------------------------
__global__ __launch_bounds__(256)
void stats_part(const float* __restrict__ Z, float* __restrict__ ps,
                float* __restrict__ pq, int M, int C, int chunks)
{
    int lc = threadIdx.x & 63;
    int col = blockIdx.x * 64 + lc;
    int rg = threadIdx.x >> 6;  // 0..3
    int rpc = M / chunks;
    int r0 = blockIdx.y * rpc;
    float s = 0.f, q = 0.f;
    for (int r = r0 + rg; r < r0 + rpc; r += 4) {
        float v = Z[(size_t)r * C + col];
        s += v; q += v * v;
    }
    __shared__ float ls[4][64], lq[4][64];
    ls[rg][lc] = s; lq[rg][lc] = q;
    __syncthreads();
    if (rg == 0) {
        float S = ls[0][lc] + ls[1][lc] + ls[2][lc] + ls[3][lc];
        float Q = lq[0][lc] + lq[1][lc] + lq[2][lc] + lq[3][lc];
        ps[(size_t)blockIdx.y * C + col] = S;
        pq[(size_t)blockIdx.y * C + col] = Q;
    }
}

__global__ void stats_fin(const float* __restrict__ ps, const float* __restrict__ pq,
                          const float* __restrict__ g, const float* __restrict__ be,
                          float* __restrict__ scale, float* __restrict__ shift,
                          int C, int M, int chunks)
{
    int c = blockIdx.x * blockDim.x + threadIdx.x;
    if (c >= C) return;
    float S = 0.f, Q = 0.f;
    for (int i = 0; i < chunks; ++i) { S += ps[(size_t)i * C + c]; Q += pq[(size_t)i * C + c]; }
    float inv = 1.0f / (float)M;
    float mean = S * inv;
    float var = Q * inv - mean * mean;
    float rstd = 1.0f / sqrtf(var + EPSBN);
    float sc = g[c] * rstd;
    scale[c] = sc;
    shift[c] = be[c] - mean * sc;
}

// ---------------------------------------------------------------------------
// Fused 15-iteration ADMM projection. One thread per batch row; all state in
// registers. A_control applied via its stencil/prefix structure (O(50)/pass).
// ---------------------------------------------------------------------------
__global__ __launch_bounds__(64, 1)
void iter_k(const float* __restrict__ X, const float* __restrict__ NN,
            const float* __restrict__ Mi, float* __restrict__ out)
{
    int row = blockIdx.x * 64 + threadIdx.x;
    float xi[50], lam[50], xin[50], rhs[50], xv[50];
#pragma unroll
    for (int k = 0; k < 50; ++k) {
        xi[k]  = NN[(size_t)row * 100 + k];
        lam[k] = NN[(size_t)row * 100 + 50 + k];
        xv[k]  = X[(size_t)row * 50 + k];
    }
    float fps = 0.f, prs = 0.f;

#pragma unroll 1
    for (int it = 0; it < 15; ++it) {
        // ---- pass 1: rhs = lam + x + A^T min(b, A xi)
#pragma unroll
        for (int k = 0; k < 50; ++k) rhs[k] = 0.f;
        {
            float pre = 0.f, Spre = 0.f, ap = 0.f;
#pragma unroll
            for (int k = 0; k < 50; ++k) {
                float yk = xi[k];
                rhs[k] += fminf(VMAX, yk) - fminf(VMAX, -yk);      // vel
                rhs[k] -= TF * Spre;                                // pos adjoint (prefix part)
                pre += yk;
                float p = TF * pre;
                Spre += fminf(PMAX, p) - fminf(PMAX, -p);
                if (k < 49) {
                    float a = AF * (xi[k + 1] - yk);
                    float da = fminf(AMAX, a) - fminf(AMAX, -a);
                    rhs[k] -= AF * da; rhs[k + 1] += AF * da;
                    if (k >= 1) {
                        float j = AF * (a - ap);
                        float dj = fminf(JMAX, j) - fminf(JMAX, -j);
                        rhs[k - 1] += JF * dj; rhs[k] -= 2.f * JF * dj; rhs[k + 1] += JF * dj;
                    }
                    ap = a;
                }
            }
#pragma unroll
            for (int k = 0; k < 50; ++k)
                rhs[k] = lam[k] + xv[k] + (rhs[k] + TF * Spre);     // RHO = 1
        }
        // ---- xin = M * rhs   (M = Qinv[0:50,0:50], uniform scalar loads)
#pragma unroll
        for (int j = 0; j < 50; ++j) {
            float s = 0.f;
#pragma unroll
            for (int k = 0; k < 50; ++k) s += Mi[j * 50 + k] * rhs[k];
            xin[j] = s;
        }
        // ---- pass 2: residuals, norms, lambda update
        float res2 = 0.f, ds2 = 0.f, dxi2 = 0.f, dlam2 = 0.f;
#pragma unroll
        for (int k = 0; k < 50; ++k) rhs[k] = 0.f;   // reuse as g
        {
            float preo = 0.f, pren = 0.f, SpreF = 0.f, aop = 0.f, anp = 0.f;
#pragma unroll
            for (int k = 0; k < 50; ++k) {
                float yo = xi[k], yn = xin[k];
                float d = yo - yn; dxi2 += d * d;
                // vel (b = VMAX)
                float rp = fmaxf(yn - VMAX, 0.f), rm = fmaxf(-yn - VMAX, 0.f);
                res2 += rp * rp + rm * rm;
                float so = fmaxf(VMAX - yo, 0.f), sn = fmaxf(VMAX - yn, 0.f);
                d = so - sn; ds2 += d * d;
                so = fmaxf(VMAX + yo, 0.f); sn = fmaxf(VMAX + yn, 0.f);
                d = so - sn; ds2 += d * d;
                rhs[k] += rp - rm;
                // pos (b = PMAX)
                rhs[k] -= TF * SpreF;
                preo += yo; pren += yn;
                float po = TF * preo, pn = TF * pren;
                rp = fmaxf(pn - PMAX, 0.f); rm = fmaxf(-pn - PMAX, 0.f);
                res2 += rp * rp + rm * rm;
                so = fmaxf(PMAX - po, 0.f); sn = fmaxf(PMAX - pn, 0.f);
                d = so - sn; ds2 += d * d;
                so = fmaxf(PMAX + po, 0.f); sn = fmaxf(PMAX + pn, 0.f);
                d = so - sn; ds2 += d * d;
                SpreF += rp - rm;
                if (k < 49) {
                    float ao = AF * (xi[k + 1] - yo), an = AF * (xin[k + 1] - yn);
                    rp = fmaxf(an - AMAX, 0.f); rm = fmaxf(-an - AMAX, 0.f);
                    res2 += rp * rp + rm * rm;
                    so = fmaxf(AMAX - ao, 0.f); sn = fmaxf(AMAX - an, 0.f);
                    d = so - sn; ds2 += d * d;
                    so = fmaxf(AMAX + ao, 0.f); sn = fmaxf(AMAX + an, 0.f);
                    d = so - sn; ds2 += d * d;
                    float fa = rp - rm; rhs[k] -= AF * fa; rhs[k + 1] += AF * fa;
                    if (k >= 1) {
                        float jo = AF * (ao - aop), jn = AF * (an - anp);
                        rp = fmaxf(jn - JMAX, 0.f); rm = fmaxf(-jn - JMAX, 0.f);
                        res2 += rp * rp + rm * rm;
                        so = fmaxf(JMAX - jo, 0.f); sn = fmaxf(JMAX - jn, 0.f);
                        d = so - sn; ds2 += d * d;
                        so = fmaxf(JMAX + jo, 0.f); sn = fmaxf(JMAX + jn, 0.f);
                        d = so - sn; ds2 += d * d;
                        float fj = rp - rm;
                        rhs[k - 1] += JF * fj; rhs[k] -= 2.f * JF * fj; rhs[k + 1] += JF * fj;
                    }
                    aop = ao; anp = an;
                }
            }
#pragma unroll
            for (int k = 0; k < 50; ++k) {
                float gk = rhs[k] + TF * SpreF;   // RHO = 1
                dlam2 += gk * gk;
                lam[k] -= gk;
            }
        }
        prs += sqrtf(res2);
        fps += sqrtf(dxi2) + sqrtf(dlam2) + sqrtf(ds2);
#pragma unroll
        for (int k = 0; k < 50; ++k) xi[k] = xin[k];
    }
#pragma unroll
    for (int k = 0; k < 50; ++k) out[(size_t)row * 50 + k] = xi[k];
    out[(size_t)BATCH * 50 + row] = fps * (1.f / 15.f);
    out[(size_t)BATCH * 51 + row] = prs * (1.f / 15.f);
}

// ---------------------------------------------------------------------------
extern "C" void kernel_launch(void* const* d_in, const int* in_sizes, int n_in,
                              void* d_out, int out_size, void* d_ws, size_t ws_size,
                              hipStream_t stream)
{
    const float* x   = (const float*)d_in[0];
    const float* W1  = (const float*)d_in[1];
    const float* b1  = (const float*)d_in[2];
    const float* g1  = (const float*)d_in[3];
    const float* be1 = (const float*)d_in[4];
    const float* W2  = (const float*)d_in[5];
    const float* b2  = (const float*)d_in[6];
    const float* g2  = (const float*)d_in[7];
    const float* be2 = (const float*)d_in[8];
    const float* W3  = (const float*)d_in[9];
    const float* b3  = (const float*)d_in[10];
    const float* g3  = (const float*)d_in[11];
    const float* be3 = (const float*)d_in[12];
    const float* W4  = (const float*)d_in[13];
    const float* b4  = (const float*)d_in[14];

    // Resolve device-global scratch (passive queries; graph-capture safe).
    float *z1, *z2, *ps, *pq, *scb, *shb, *Mi;
    hipGetSymbolAddress((void**)&z1,  HIP_SYMBOL(g_z1));
    hipGetSymbolAddress((void**)&z2,  HIP_SYMBOL(g_z2));
    hipGetSymbolAddress((void**)&ps,  HIP_SYMBOL(g_ps));
    hipGetSymbolAddress((void**)&pq,  HIP_SYMBOL(g_pq));
    hipGetSymbolAddress((void**)&scb, HIP_SYMBOL(g_scale));
    hipGetSymbolAddress((void**)&shb, HIP_SYMBOL(g_shift));
    hipGetSymbolAddress((void**)&Mi,  HIP_SYMBOL(g_Mi));

    float* z3  = z1;                       // reuse z1 (dead after GEMM2)
    float* nno = z1 + (size_t)BATCH * H3;  // 32768*100, after z3 within z1
    float* sc1 = scb;       float* sh1 = shb;
    float* sc2 = scb + 1024; float* sh2 = shb + 1024;
    float* sc3 = scb + 2048; float* sh3 = shb + 2048;

    hipLaunchKernelGGL(build_M, dim3(1), dim3(64), 0, stream, Mi);

    dim3 blk(256);
    // L1: z1 = x @ W1 + b1
    hipLaunchKernelGGL((gemm_k<0>), dim3(BATCH / 128, H1 / 128), blk, 0, stream,
                       x, W1, b1, (const float*)nullptr, (const float*)nullptr,
                       z1, BATCH, NVARS, H1);
    hipLaunchKernelGGL(stats_part, dim3(H1 / 64, 32), blk, 0, stream, z1, ps, pq, BATCH, H1, 32);
    hipLaunchKernelGGL(stats_fin, dim3(4), dim3(256), 0, stream, ps, pq, g1, be1, sc1, sh1, H1, BATCH, 32);
    // L2: z2 = relu(bn(z1)) @ W2 + b2
    hipLaunchKernelGGL((gemm_k<1>), dim3(BATCH / 128, H2 / 128), blk, 0, stream,
                       z1, W2, b2, sc1, sh1, z2, BATCH, H1, H2);
    hipLaunchKernelGGL(stats_part, dim3(H2 / 64, 32), blk, 0, stream, z2, ps, pq, BATCH, H2, 32);
    hipLaunchKernelGGL(stats_fin, dim3(4), dim3(256), 0, stream, ps, pq, g2, be2, sc2, sh2, H2, BATCH, 32);
    // L3: z3 = relu(bn(z2)) @ W3 + b3
    hipLaunchKernelGGL((gemm_k<1>), dim3(BATCH / 128, H3 / 128), blk, 0, stream,
                       z2, W3, b3, sc2, sh2, z3, BATCH, H2, H3);
    hipLaunchKernelGGL(stats_part, dim3(H3 / 64, 32), blk, 0, stream, z3, ps, pq, BATCH, H3, 32);
    hipLaunchKernelGGL(stats_fin, dim3(1), dim3(256), 0, stream, ps, pq, g3, be3, sc3, sh3, H3, BATCH, 32);
    // L4: nno = relu(bn(z3)) @ W4 + b4
    hipLaunchKernelGGL((gemm_k<1>), dim3(BATCH / 128, 1), blk, 0, stream,
                       z3, W4, b4, sc3, sh3, nno, BATCH, H3, NOUT);
    // fused ADMM iterations
    hipLaunchKernelGGL(iter_k, dim3(BATCH / 64), dim3(64), 0, stream,
                       x, nno, Mi, (float*)d_out);
}

// Round 3
// 1866.940 us; speedup vs baseline: 2.1490x; 2.1490x over previous
//
#include <hip/hip_runtime.h>
#include <math.h>

#define BATCH 32768
#define NVARS 50
#define H1 1024
#define H2 1024
#define H3 256
#define NOUT 100
#define EPSBN 1e-5f

#define TF   0.05f
#define AF   20.0f
#define JF   400.0f
#define VMAX 1.0f
#define AMAX 2.0f
#define JMAX 5.0f
#define PMAX 3.14159265358979323846f

typedef unsigned short ushort_t;
typedef __attribute__((ext_vector_type(8))) short short8;
typedef __attribute__((ext_vector_type(4))) float f32x4;

// ---------------------------------------------------------------------------
// Device-global scratch (no ws_size dependence).
// ---------------------------------------------------------------------------
__device__ float g_z1[(size_t)BATCH * H1];   // z1 / (z3, nno reuse)
__device__ float g_z2[(size_t)BATCH * H2];
__device__ float g_ps[32 * 1024];
__device__ float g_pq[32 * 1024];
__device__ float g_scale[3 * 1024];
__device__ float g_shift[3 * 1024];
__device__ float g_Mi[2500];
__device__ ushort_t g_w2h[(size_t)H1 * H2], g_w2m[(size_t)H1 * H2], g_w2l[(size_t)H1 * H2];
__device__ ushort_t g_w3h[(size_t)H2 * H3], g_w3m[(size_t)H2 * H3], g_w3l[(size_t)H2 * H3];

// ---------------------------------------------------------------------------
// float -> bf16 triple split (RNE), f ~= hi + mid + lo with rel err ~2^-26.
// ---------------------------------------------------------------------------
__device__ __forceinline__ void split3(float f, ushort_t& h, ushort_t& m, ushort_t& l)
{
    unsigned u = __float_as_uint(f);
    unsigned r = u + 0x7fffu + ((u >> 16) & 1u);
    h = (ushort_t)(r >> 16);
    float f1 = f - __uint_as_float((unsigned)h << 16);
    unsigned u1 = __float_as_uint(f1);
    unsigned r1 = u1 + 0x7fffu + ((u1 >> 16) & 1u);
    m = (ushort_t)(r1 >> 16);
    float f2 = f1 - __uint_as_float((unsigned)m << 16);
    unsigned u2 = __float_as_uint(f2);
    unsigned r2 = u2 + 0x7fffu + ((u2 >> 16) & 1u);
    l = (ushort_t)(r2 >> 16);
}

// ---------------------------------------------------------------------------
// Build M = Q_inv[0:50,0:50] via f64 Gauss-Jordan with partial pivoting.
// Init parallelized across 64 lanes with closed-form Q entries (bit-identical
// f64 values to the incremental version: all non-pos terms are exact ints).
// ---------------------------------------------------------------------------
__global__ void build_M(float* __restrict__ Mout)
{
    __shared__ double aug[52][104];
    __shared__ int piv;
    int tid = threadIdx.x;

    const double Tf = (double)0.05f;           // float-rounded T, as numpy f32 cast
    const double c3[3] = { 400.0, -800.0, 400.0 };

    for (int idx = tid; idx < 52 * 104; idx += 64) {
        int j = idx / 104, k = idx % 104;
        double v = 0.0;
        if (k >= 52) {
            v = (k == 52 + j) ? 1.0 : 0.0;
        } else if (j < 50 && k < 50) {
            double q = (j == k) ? 3.0 : 0.0;                       // I + 2*velT*vel
            if (j == k) q += 800.0 * ((j < 49 ? 1 : 0) + (j > 0 ? 1 : 0));
            if (j - k == 1 || k - j == 1) q += -800.0;             // acc off-diag
            int lo = j > k ? j : k; lo -= 2; if (lo < 0) lo = 0;
            int hi = j < k ? j : k; if (hi > 47) hi = 47;
            for (int i = lo; i <= hi; ++i) {
                int dj = j - i, dk = k - i;
                if (dj >= 0 && dj <= 2 && dk >= 0 && dk <= 2)
                    q += 2.0 * c3[dj] * c3[dk];
            }
            int mx = j > k ? j : k;
            q += 2.0 * Tf * Tf * (double)(50 - mx);                // pos block (added last)
            v = q;
        } else if ((j == 50 && k == 0) || (j == 0 && k == 50) ||
                   (j == 51 && k == 49) || (j == 49 && k == 51)) {
            v = 1.0;
        }
        aug[j][k] = v;
    }
    __syncthreads();

    for (int c = 0; c < 52; ++c) {
        if (tid == 0) {
            int p = c; double best = fabs(aug[c][c]);
            for (int r = c + 1; r < 52; ++r) {
                double v = fabs(aug[r][c]);
                if (v > best) { best = v; p = r; }
            }
            piv = p;
        }
        __syncthreads();
        int p = piv;
        if (p != c) {
            for (int k = tid; k < 104; k += 64) {
                double t = aug[c][k]; aug[c][k] = aug[p][k]; aug[p][k] = t;
            }
        }
        __syncthreads();
        double pv = aug[c][c];
        __syncthreads();
        for (int k = tid; k < 104; k += 64) aug[c][k] /= pv;
        __syncthreads();
        if (tid < 52 && tid != c) {
            double f = aug[tid][c];
            for (int k = 0; k < 104; ++k) aug[tid][k] -= f * aug[c][k];
        }
        __syncthreads();
    }

    for (int idx = tid; idx < 2500; idx += 64) {
        int j = idx / 50, k = idx % 50;
        Mout[idx] = (float)aug[j][52 + k];
    }
}

// ---------------------------------------------------------------------------
// Transpose + triple-split W[K][N] f32 -> Wt{h,m,l}[N][K] bf16.
// ---------------------------------------------------------------------------
__global__ __launch_bounds__(256)
void wsplit(const float* __restrict__ W, ushort_t* __restrict__ WH,
            ushort_t* __restrict__ WM, ushort_t* __restrict__ WL, int K, int N)
{
    __shared__ float tile[32][33];
    int t = threadIdx.x;
    int n0 = blockIdx.x * 32, k0 = blockIdx.y * 32;
    int rr = t >> 5, cc = t & 31;
#pragma unroll
    for (int i = 0; i < 4; ++i)
        tile[rr + i * 8][cc] = W[(size_t)(k0 + rr + i * 8) * N + n0 + cc];
    __syncthreads();
#pragma unroll
    for (int i = 0; i < 4; ++i) {
        int n = n0 + rr + i * 8, k = k0 + cc;
        float f = tile[cc][rr + i * 8];
        ushort_t h, m, l;
        split3(f, h, m, l);
        WH[(size_t)n * K + k] = h;
        WM[(size_t)n * K + k] = m;
        WL[(size_t)n * K + k] = l;
    }
}

// ---------------------------------------------------------------------------
// MFMA GEMM, fp32-emulated via bf16 triple split (6 MFMAs per frag pair).
// C[M,N] = relu(A*scale+shift) @ W + bias   (A fp32, W pre-split bf16 [N][K])
// BM=BN=128, BK=32, 256 threads (4 waves as 2x2 of 64x64).
// LDS rows padded to 80 B (32 bf16 data + 16 B) to spread banks.
// ---------------------------------------------------------------------------
template <int BN_APPLY>
__global__ __launch_bounds__(256)
void gemm_mfma(const float* __restrict__ A,
               const ushort_t* __restrict__ WH, const ushort_t* __restrict__ WM,
               const ushort_t* __restrict__ WL,
               const float* __restrict__ bias,
               const float* __restrict__ scale, const float* __restrict__ shift,
               float* __restrict__ C, int M, int K, int N)
{
    const int TIER = 128 * 80;
    __shared__ __attribute__((aligned(16))) unsigned char lds[6 * 128 * 80];
    char* Lb = (char*)lds;

    const int t = threadIdx.x;
    const int r = t >> 1, kh = t & 1;           // staging: row/col slot + k half
    const int row0 = blockIdx.x * 128, col0 = blockIdx.y * 128;

    const float*    Ab  = A  + (size_t)(row0 + r) * K + kh * 16;
    const ushort_t* WHb = WH + (size_t)(col0 + r) * K + kh * 16;
    const ushort_t* WMb = WM + (size_t)(col0 + r) * K + kh * 16;
    const ushort_t* WLb = WL + (size_t)(col0 + r) * K + kh * 16;
    const int awb = r * 80 + kh * 32;

    const int lane = t & 63, w = t >> 6;
    const int wm = w >> 1, wn = w & 1;
    const int fr = lane & 15, fg = lane >> 4;
    const int aoff = (wm * 64 + fr) * 80 + fg * 16;
    const int boff = 3 * TIER + (wn * 64 + fr) * 80 + fg * 16;

    f32x4 acc[4][4];
#pragma unroll
    for (int m = 0; m < 4; ++m)
#pragma unroll
        for (int n = 0; n < 4; ++n)
#pragma unroll
            for (int q = 0; q < 4; ++q) acc[m][n][q] = 0.f;

    for (int k0 = 0; k0 < K; k0 += 32) {
        // ---- stage A (fp32 -> BN/relu -> split3 -> 3 LDS tiers)
        float4 f[4];
#pragma unroll
        for (int i = 0; i < 4; ++i) f[i] = *(const float4*)(Ab + k0 + i * 4);
        if (BN_APPLY) {
#pragma unroll
            for (int i = 0; i < 4; ++i) {
                float4 sc = *(const float4*)(scale + k0 + kh * 16 + i * 4);
                float4 sh = *(const float4*)(shift + k0 + kh * 16 + i * 4);
                f[i].x = fmaxf(f[i].x * sc.x + sh.x, 0.f);
                f[i].y = fmaxf(f[i].y * sc.y + sh.y, 0.f);
                f[i].z = fmaxf(f[i].z * sc.z + sh.z, 0.f);
                f[i].w = fmaxf(f[i].w * sc.w + sh.w, 0.f);
            }
        }
        ushort_t hh[16], mm[16], ll[16];
#pragma unroll
        for (int i = 0; i < 4; ++i) {
            split3(f[i].x, hh[i*4+0], mm[i*4+0], ll[i*4+0]);
            split3(f[i].y, hh[i*4+1], mm[i*4+1], ll[i*4+1]);
            split3(f[i].z, hh[i*4+2], mm[i*4+2], ll[i*4+2]);
            split3(f[i].w, hh[i*4+3], mm[i*4+3], ll[i*4+3]);
        }
#define PK(a,b) (((unsigned)(a)) | (((unsigned)(b)) << 16))
        *(uint4*)(Lb + awb)              = make_uint4(PK(hh[0],hh[1]), PK(hh[2],hh[3]), PK(hh[4],hh[5]), PK(hh[6],hh[7]));
        *(uint4*)(Lb + awb + 16)         = make_uint4(PK(hh[8],hh[9]), PK(hh[10],hh[11]), PK(hh[12],hh[13]), PK(hh[14],hh[15]));
        *(uint4*)(Lb + TIER + awb)       = make_uint4(PK(mm[0],mm[1]), PK(mm[2],mm[3]), PK(mm[4],mm[5]), PK(mm[6],mm[7]));
        *(uint4*)(Lb + TIER + awb + 16)  = make_uint4(PK(mm[8],mm[9]), PK(mm[10],mm[11]), PK(mm[12],mm[13]), PK(mm[14],mm[15]));
        *(uint4*)(Lb + 2*TIER + awb)     = make_uint4(PK(ll[0],ll[1]), PK(ll[2],ll[3]), PK(ll[4],ll[5]), PK(ll[6],ll[7]));
        *(uint4*)(Lb + 2*TIER + awb + 16)= make_uint4(PK(ll[8],ll[9]), PK(ll[10],ll[11]), PK(ll[12],ll[13]), PK(ll[14],ll[15]));
#undef PK
        // ---- stage W (already bf16, copy 3 tiers)
        {
            const uint4* p0 = (const uint4*)(WHb + k0);
            const uint4* p1 = (const uint4*)(WMb + k0);
            const uint4* p2 = (const uint4*)(WLb + k0);
            *(uint4*)(Lb + 3*TIER + awb)      = p0[0];
            *(uint4*)(Lb + 3*TIER + awb + 16) = p0[1];
            *(uint4*)(Lb + 4*TIER + awb)      = p1[0];
            *(uint4*)(Lb + 4*TIER + awb + 16) = p1[1];
            *(uint4*)(Lb + 5*TIER + awb)      = p2[0];
            *(uint4*)(Lb + 5*TIER + awb + 16) = p2[1];
        }
        __syncthreads();

        short8 ah[4], am4[4], al4[4], bh[4], bm4[4], bl4[4];
#pragma unroll
        for (int m = 0; m < 4; ++m) {
            ah[m]  = *(short8*)(Lb + aoff + m * 1280);
            am4[m] = *(short8*)(Lb + TIER + aoff + m * 1280);
            al4[m] = *(short8*)(Lb + 2 * TIER + aoff + m * 1280);
        }
#pragma unroll
        for (int n = 0; n < 4; ++n) {
            bh[n]  = *(short8*)(Lb + boff + n * 1280);
            bm4[n] = *(short8*)(Lb + TIER + boff + n * 1280);
            bl4[n] = *(short8*)(Lb + 2 * TIER + boff + n * 1280);
        }
#pragma unroll
        for (int m = 0; m < 4; ++m)
#pragma unroll
            for (int n = 0; n < 4; ++n) {
                f32x4 c = acc[m][n];
                c = __builtin_amdgcn_mfma_f32_16x16x32_bf16(al4[m], bh[n],  c, 0, 0, 0);
                c = __builtin_amdgcn_mfma_f32_16x16x32_bf16(ah[m],  bl4[n], c, 0, 0, 0);
                c = __builtin_amdgcn_mfma_f32_16x16x32_bf16(am4[m], bm4[n], c, 0, 0, 0);
                c = __builtin_amdgcn_mfma_f32_16x16x32_bf16(am4[m], bh[n],  c, 0, 0, 0);
                c = __builtin_amdgcn_mfma_f32_16x16x32_bf16(ah[m],  bm4[n], c, 0, 0, 0);
                c = __builtin_amdgcn_mfma_f32_16x16x32_bf16(ah[m],  bh[n],  c, 0, 0, 0);
                acc[m][n] = c;
            }
        __syncthreads();
    }

#pragma unroll
    for (int m = 0; m < 4; ++m)
#pragma unroll
        for (int n = 0; n < 4; ++n) {
            int cc = col0 + wn * 64 + n * 16 + fr;
            float b = bias[cc];
#pragma unroll
            for (int q = 0; q < 4; ++q) {
                int rr = row0 + wm * 64 + m * 16 + fg * 4 + q;
                C[(size_t)rr * N + cc] = acc[m][n][q] + b;
            }
        }
}

// ---------------------------------------------------------------------------
// fp32 tiled GEMM (kept for GEMM1 K=50 and GEMM4 N=100).
// ---------------------------------------------------------------------------
template <int BN_APPLY>
__global__ __launch_bounds__(256)
void gemm_k(const float* __restrict__ A, const float* __restrict__ W,
            const float* __restrict__ bias,
            const float* __restrict__ scale, const float* __restrict__ shift,
            float* __restrict__ C, int M, int K, int N)
{
    const int BM = 128, BN = 128, BK = 16;
    __shared__ __attribute__((aligned(16))) float As[BK][BM + 4];
    __shared__ __attribute__((aligned(16))) float Ws[BK][BN];
    int tid = threadIdx.x;
    int tm = tid >> 4, tn = tid & 15;
    int row0 = blockIdx.x * BM, col0 = blockIdx.y * BN;

    float acc[8][8];
#pragma unroll
    for (int i = 0; i < 8; ++i)
#pragma unroll
        for (int j = 0; j < 8; ++j) acc[i][j] = 0.f;

    int alr = tid >> 4;
    int alk = tid & 15;
    int wlc = tid & 127;
    int wlk = tid >> 7;

    for (int k0 = 0; k0 < K; k0 += BK) {
#pragma unroll
        for (int i = 0; i < 8; ++i) {
            int rr = row0 + alr + i * 16;
            int kk = k0 + alk;
            float v = 0.f;
            if (kk < K) {
                v = A[(size_t)rr * K + kk];
                if (BN_APPLY) v = fmaxf(v * scale[kk] + shift[kk], 0.f);
            }
            As[alk][alr + i * 16] = v;
        }
#pragma unroll
        for (int i = 0; i < 8; ++i) {
            int kk = k0 + wlk + i * 2;
            int cc = col0 + wlc;
            Ws[wlk + i * 2][wlc] = (kk < K && cc < N) ? W[(size_t)kk * N + cc] : 0.f;
        }
        __syncthreads();
#pragma unroll
        for (int kk = 0; kk < BK; ++kk) {
            float av[8], wv[8];
            float4 tv;
            tv = *(const float4*)&As[kk][tm * 8];     av[0]=tv.x; av[1]=tv.y; av[2]=tv.z; av[3]=tv.w;
            tv = *(const float4*)&As[kk][tm * 8 + 4]; av[4]=tv.x; av[5]=tv.y; av[6]=tv.z; av[7]=tv.w;
            tv = *(const float4*)&Ws[kk][tn * 8];     wv[0]=tv.x; wv[1]=tv.y; wv[2]=tv.z; wv[3]=tv.w;
            tv = *(const float4*)&Ws[kk][tn * 8 + 4]; wv[4]=tv.x; wv[5]=tv.y; wv[6]=tv.z; wv[7]=tv.w;
#pragma unroll
            for (int i = 0; i < 8; ++i)
#pragma unroll
                for (int j = 0; j < 8; ++j) acc[i][j] += av[i] * wv[j];
        }
        __syncthreads();
    }
#pragma unroll
    for (int i = 0; i < 8; ++i) {
        int rr = row0 + tm * 8 + i;
#pragma unroll
        for (int j = 0; j < 8; ++j) {
            int cc = col0 + tn * 8 + j;
            if (cc < N) C[(size_t)rr * N + cc] = acc[i][j] + bias[cc];
        }
    }
}

// ---------------------------------------------------------------------------
// BatchNorm stats.
// ---------------------------------------------------------------------------
__global__ __launch_bounds__(256)
void stats_part(const float* __restrict__ Z, float* __restrict__ ps,
                float* __restrict__ pq, int M, int C, int chunks)
{
    int lc = threadIdx.x & 63;
    int col = blockIdx.x * 64 + lc;
    int rg = threadIdx.x >> 6;
    int rpc = M / chunks;
    int r0 = blockIdx.y * rpc;
    float s = 0.f, q = 0.f;
    for (int rr = r0 + rg; rr < r0 + rpc; rr += 4) {
        float v = Z[(size_t)rr * C + col];
        s += v; q += v * v;
    }
    __shared__ float ls[4][64], lq[4][64];
    ls[rg][lc] = s; lq[rg][lc] = q;
    __syncthreads();
    if (rg == 0) {
        float S = ls[0][lc] + ls[1][lc] + ls[2][lc] + ls[3][lc];
        float Q = lq[0][lc] + lq[1][lc] + lq[2][lc] + lq[3][lc];
        ps[(size_t)blockIdx.y * C + col] = S;
        pq[(size_t)blockIdx.y * C + col] = Q;
    }
}

__global__ void stats_fin(const float* __restrict__ ps, const float* __restrict__ pq,
                          const float* __restrict__ g, const float* __restrict__ be,
                          float* __restrict__ scale, float* __restrict__ shift,
                          int C, int M, int chunks)
{
    int c = blockIdx.x * blockDim.x + threadIdx.x;
    if (c >= C) return;
    float S = 0.f, Q = 0.f;
    for (int i = 0; i < chunks; ++i) { S += ps[(size_t)i * C + c]; Q += pq[(size_t)i * C + c]; }
    float inv = 1.0f / (float)M;
    float mean = S * inv;
    float var = Q * inv - mean * mean;
    float rstd = 1.0f / sqrtf(var + EPSBN);
    float sc = g[c] * rstd;
    scale[c] = sc;
    shift[c] = be[c] - mean * sc;
}

// ---------------------------------------------------------------------------
// Fused 15-iteration ADMM. State in LDS [k][lane] (stride 64 -> bank-free),
// rolled loops with sliding-register windows => ~2 KB hot loop, no scratch.
// ---------------------------------------------------------------------------
__global__ __launch_bounds__(64)
void iter_k(const float* __restrict__ X, const float* __restrict__ NN,
            const float* __restrict__ Mi, float* __restrict__ out)
{
    __shared__ float sA[50 * 64];
    __shared__ float sB[50 * 64];
    __shared__ float sL[50 * 64];
    __shared__ float sX[50 * 64];
    __shared__ float sG[50 * 64];
    const int lane = threadIdx.x;
    const int row = blockIdx.x * 64 + lane;
#define IDX(k) (((k) << 6) + lane)

#pragma unroll 1
    for (int k = 0; k < 50; ++k) {
        sA[IDX(k)] = NN[(size_t)row * 100 + k];
        sL[IDX(k)] = NN[(size_t)row * 100 + 50 + k];
        sX[IDX(k)] = X[(size_t)row * 50 + k];
    }
    float* cx = sA;
    float* cn = sB;
    float fps = 0.f, prs = 0.f;

#pragma unroll 1
    for (int it = 0; it < 15; ++it) {
        // ---- pass 1: sG[k] = (A^T min(b, A xi))[k]  (pos suffix via Stot)
        float pre = 0.f, Sp = 0.f, ap = 0.f;
        float r_m = 0.f, r_c = 0.f, r_p = 0.f;
        float xc = cx[IDX(0)];
#pragma unroll 1
        for (int k = 0; k < 49; ++k) {
            float xn = cx[IDX(k + 1)];
            r_c += fminf(VMAX, xc) - fminf(VMAX, -xc);
            r_c -= TF * Sp;
            pre += xc;
            float p = TF * pre;
            Sp += fminf(PMAX, p) - fminf(PMAX, -p);
            float a = AF * (xn - xc);
            float da = fminf(AMAX, a) - fminf(AMAX, -a);
            r_c -= AF * da; r_p += AF * da;
            if (k >= 1) {
                float j = AF * (a - ap);
                float dj = fminf(JMAX, j) - fminf(JMAX, -j);
                r_m += JF * dj; r_c -= 2.f * JF * dj; r_p += JF * dj;
            }
            ap = a;
            if (k >= 1) sG[IDX(k - 1)] = r_m;
            r_m = r_c; r_c = r_p; r_p = 0.f;
            xc = xn;
        }
        // k = 49 (vel + pos only)
        r_c += fminf(VMAX, xc) - fminf(VMAX, -xc);
        r_c -= TF * Sp;
        pre += xc;
        { float p = TF * pre; Sp += fminf(PMAX, p) - fminf(PMAX, -p); }
        sG[IDX(48)] = r_m;
        sG[IDX(49)] = r_c;
        float Stot = TF * Sp;

        // ---- rhs into 50 named registers
        float rh[50];
#pragma unroll
        for (int k = 0; k < 50; ++k)
            rh[k] = sG[IDX(k)] + sL[IDX(k)] + sX[IDX(k)] + Stot;

        // ---- xin = M * rhs (M rows via scalar loads; rhs in regs)
#pragma unroll 1
        for (int j = 0; j < 50; ++j) {
            float acc = 0.f;
#pragma unroll
            for (int k = 0; k < 50; ++k) acc += Mi[j * 50 + k] * rh[k];
            cn[IDX(j)] = acc;
        }

        // ---- pass 2: residual/s norms, g into sG
        float res2 = 0.f, ds2 = 0.f, dxi2 = 0.f, dlam2 = 0.f;
        float preo = 0.f, pren = 0.f, SpF = 0.f, aop = 0.f, anp = 0.f;
        float g_m = 0.f, g_c = 0.f, g_p = 0.f;
        float xoc = cx[IDX(0)], xnc = cn[IDX(0)];
#pragma unroll 1
        for (int k = 0; k < 49; ++k) {
            float xon = cx[IDX(k + 1)], xnn = cn[IDX(k + 1)];
            float d = xoc - xnc; dxi2 += d * d;
            float rp = fmaxf(xnc - VMAX, 0.f), rm = fmaxf(-xnc - VMAX, 0.f);
            res2 += rp * rp + rm * rm;
            float so = fmaxf(VMAX - xoc, 0.f), sn = fmaxf(VMAX - xnc, 0.f);
            d = so - sn; ds2 += d * d;
            so = fmaxf(VMAX + xoc, 0.f); sn = fmaxf(VMAX + xnc, 0.f);
            d = so - sn; ds2 += d * d;
            g_c += rp - rm;
            g_c -= TF * SpF;
            preo += xoc; pren += xnc;
            float po = TF * preo, pn = TF * pren;
            rp = fmaxf(pn - PMAX, 0.f); rm = fmaxf(-pn - PMAX, 0.f);
            res2 += rp * rp + rm * rm;
            so = fmaxf(PMAX - po, 0.f); sn = fmaxf(PMAX - pn, 0.f);
            d = so - sn; ds2 += d * d;
            so = fmaxf(PMAX + po, 0.f); sn = fmaxf(PMAX + pn, 0.f);
            d = so - sn; ds2 += d * d;
            SpF += rp - rm;
            float ao = AF * (xon - xoc), an = AF * (xnn - xnc);
            rp = fmaxf(an - AMAX, 0.f); rm = fmaxf(-an - AMAX, 0.f);
            res2 += rp * rp + rm * rm;
            so = fmaxf(AMAX - ao, 0.f); sn = fmaxf(AMAX - an, 0.f);
            d = so - sn; ds2 += d * d;
            so = fmaxf(AMAX + ao, 0.f); sn = fmaxf(AMAX + an, 0.f);
            d = so - sn; ds2 += d * d;
            float fa = rp - rm; g_c -= AF * fa; g_p += AF * fa;
            if (k >= 1) {
                float jo = AF * (ao - aop), jn = AF * (an - anp);
                rp = fmaxf(jn - JMAX, 0.f); rm = fmaxf(-jn - JMAX, 0.f);
                res2 += rp * rp + rm * rm;
                so = fmaxf(JMAX - jo, 0.f); sn = fmaxf(JMAX - jn, 0.f);
                d = so - sn; ds2 += d * d;
                so = fmaxf(JMAX + jo, 0.f); sn = fmaxf(JMAX + jn, 0.f);
                d = so - sn; ds2 += d * d;
                float fj = rp - rm;
                g_m += JF * fj; g_c -= 2.f * JF * fj; g_p += JF * fj;
            }
            aop = ao; anp = an;
            if (k >= 1) sG[IDX(k - 1)] = g_m;
            g_m = g_c; g_c = g_p; g_p = 0.f;
            xoc = xon; xnc = xnn;
        }
        { // k = 49
            float d = xoc - xnc; dxi2 += d * d;
            float rp = fmaxf(xnc - VMAX, 0.f), rm = fmaxf(-xnc - VMAX, 0.f);
            res2 += rp * rp + rm * rm;
            float so = fmaxf(VMAX - xoc, 0.f), sn = fmaxf(VMAX - xnc, 0.f);
            d = so - sn; ds2 += d * d;
            so = fmaxf(VMAX + xoc, 0.f); sn = fmaxf(VMAX + xnc, 0.f);
            d = so - sn; ds2 += d * d;
            g_c += rp - rm;
            g_c -= TF * SpF;
            preo += xoc; pren += xnc;
            float po = TF * preo, pn = TF * pren;
            rp = fmaxf(pn - PMAX, 0.f); rm = fmaxf(-pn - PMAX, 0.f);
            res2 += rp * rp + rm * rm;
            so = fmaxf(PMAX - po, 0.f); sn = fmaxf(PMAX - pn, 0.f);
            d = so - sn; ds2 += d * d;
            so = fmaxf(PMAX + po, 0.f); sn = fmaxf(PMAX + pn, 0.f);
            d = so - sn; ds2 += d * d;
            SpF += rp - rm;
            sG[IDX(48)] = g_m;
            sG[IDX(49)] = g_c;
        }
        float SF = TF * SpF;
#pragma unroll 1
        for (int k = 0; k < 50; ++k) {
            float gk = sG[IDX(k)] + SF;
            dlam2 += gk * gk;
            sL[IDX(k)] = sL[IDX(k)] - gk;
        }
        prs += sqrtf(res2);
        fps += sqrtf(dxi2) + sqrtf(dlam2) + sqrtf(ds2);
        float* tp = cx; cx = cn; cn = tp;
    }
#pragma unroll 1
    for (int k = 0; k < 50; ++k) out[(size_t)row * 50 + k] = cx[IDX(k)];
    out[(size_t)BATCH * 50 + row] = fps * (1.f / 15.f);
    out[(size_t)BATCH * 51 + row] = prs * (1.f / 15.f);
#undef IDX
}

// ---------------------------------------------------------------------------
extern "C" void kernel_launch(void* const* d_in, const int* in_sizes, int n_in,
                              void* d_out, int out_size, void* d_ws, size_t ws_size,
                              hipStream_t stream)
{
    const float* x   = (const float*)d_in[0];
    const float* W1  = (const float*)d_in[1];
    const float* b1  = (const float*)d_in[2];
    const float* g1  = (const float*)d_in[3];
    const float* be1 = (const float*)d_in[4];
    const float* W2  = (const float*)d_in[5];
    const float* b2  = (const float*)d_in[6];
    const float* g2  = (const float*)d_in[7];
    const float* be2 = (const float*)d_in[8];
    const float* W3  = (const float*)d_in[9];
    const float* b3  = (const float*)d_in[10];
    const float* g3  = (const float*)d_in[11];
    const float* be3 = (const float*)d_in[12];
    const float* W4  = (const float*)d_in[13];
    const float* b4  = (const float*)d_in[14];

    float *z1, *z2, *ps, *pq, *scb, *shb, *Mi;
    ushort_t *w2h, *w2m, *w2l, *w3h, *w3m, *w3l;
    hipGetSymbolAddress((void**)&z1,  HIP_SYMBOL(g_z1));
    hipGetSymbolAddress((void**)&z2,  HIP_SYMBOL(g_z2));
    hipGetSymbolAddress((void**)&ps,  HIP_SYMBOL(g_ps));
    hipGetSymbolAddress((void**)&pq,  HIP_SYMBOL(g_pq));
    hipGetSymbolAddress((void**)&scb, HIP_SYMBOL(g_scale));
    hipGetSymbolAddress((void**)&shb, HIP_SYMBOL(g_shift));
    hipGetSymbolAddress((void**)&Mi,  HIP_SYMBOL(g_Mi));
    hipGetSymbolAddress((void**)&w2h, HIP_SYMBOL(g_w2h));
    hipGetSymbolAddress((void**)&w2m, HIP_SYMBOL(g_w2m));
    hipGetSymbolAddress((void**)&w2l, HIP_SYMBOL(g_w2l));
    hipGetSymbolAddress((void**)&w3h, HIP_SYMBOL(g_w3h));
    hipGetSymbolAddress((void**)&w3m, HIP_SYMBOL(g_w3m));
    hipGetSymbolAddress((void**)&w3l, HIP_SYMBOL(g_w3l));

    float* z3  = z1;                        // z1 dead after GEMM2
    float* nno = z1 + (size_t)BATCH * H3;   // after z3
    float* sc1 = scb;        float* sh1 = shb;
    float* sc2 = scb + 1024; float* sh2 = shb + 1024;
    float* sc3 = scb + 2048; float* sh3 = shb + 2048;

    dim3 blk(256);
    hipLaunchKernelGGL(build_M, dim3(1), dim3(64), 0, stream, Mi);
    hipLaunchKernelGGL(wsplit, dim3(H2 / 32, H1 / 32), blk, 0, stream, W2, w2h, w2m, w2l, H1, H2);
    hipLaunchKernelGGL(wsplit, dim3(H3 / 32, H2 / 32), blk, 0, stream, W3, w3h, w3m, w3l, H2, H3);

    // L1: z1 = x @ W1 + b1 (fp32 vector path, K=50)
    hipLaunchKernelGGL((gemm_k<0>), dim3(BATCH / 128, H1 / 128), blk, 0, stream,
                       x, W1, b1, (const float*)nullptr, (const float*)nullptr,
                       z1, BATCH, NVARS, H1);
    hipLaunchKernelGGL(stats_part, dim3(H1 / 64, 32), blk, 0, stream, z1, ps, pq, BATCH, H1, 32);
    hipLaunchKernelGGL(stats_fin, dim3(4), dim3(256), 0, stream, ps, pq, g1, be1, sc1, sh1, H1, BATCH, 32);
    // L2: z2 = relu(bn(z1)) @ W2 + b2 (MFMA split)
    hipLaunchKernelGGL((gemm_mfma<1>), dim3(BATCH / 128, H2 / 128), blk, 0, stream,
                       z1, w2h, w2m, w2l, b2, sc1, sh1, z2, BATCH, H1, H2);
    hipLaunchKernelGGL(stats_part, dim3(H2 / 64, 32), blk, 0, stream, z2, ps, pq, BATCH, H2, 32);
    hipLaunchKernelGGL(stats_fin, dim3(4), dim3(256), 0, stream, ps, pq, g2, be2, sc2, sh2, H2, BATCH, 32);
    // L3: z3 = relu(bn(z2)) @ W3 + b3 (MFMA split)
    hipLaunchKernelGGL((gemm_mfma<1>), dim3(BATCH / 128, H3 / 128), blk, 0, stream,
                       z2, w3h, w3m, w3l, b3, sc2, sh2, z3, BATCH, H2, H3);
    hipLaunchKernelGGL(stats_part, dim3(H3 / 64, 32), blk, 0, stream, z3, ps, pq, BATCH, H3, 32);
    hipLaunchKernelGGL(stats_fin, dim3(1), dim3(256), 0, stream, ps, pq, g3, be3, sc3, sh3, H3, BATCH, 32);
    // L4: nno = relu(bn(z3)) @ W4 + b4 (fp32 vector path, N=100)
    hipLaunchKernelGGL((gemm_k<1>), dim3(BATCH / 128, 1), blk, 0, stream,
                       z3, W4, b4, sc3, sh3, nno, BATCH, H3, NOUT);
    // fused ADMM iterations
    hipLaunchKernelGGL(iter_k, dim3(BATCH / 64), dim3(64), 0, stream,
                       x, nno, Mi, (float*)d_out);
}